// Round 17
// baseline (214.479 us; speedup 1.0000x reference)
//
#include <hip/hip_runtime.h>
#include <stdint.h>

#define THR  1.0f
#define BETA 0.95f
#define SX   4096.0f            // x scale (2^12) -> no fp16 denormal flush
#define SW   512.0f             // W scale (2^9)
#define SINV (1.0f / (4096.0f * 512.0f))
#define W1N  (128 * 784)

typedef __attribute__((ext_vector_type(8)))  _Float16 f16x8;
typedef __attribute__((ext_vector_type(16))) float    f32x16;
typedef __attribute__((ext_vector_type(4)))  float    fvec4;

__device__ __forceinline__ void gll16(const float* g, float* l){
  __builtin_amdgcn_global_load_lds((const __attribute__((address_space(1))) void*)g,
                                   (__attribute__((address_space(3))) void*)l, 16, 0, 0);
}

// 2-term RNE fp16 split of scaled W1 in per-16k fragment order:
// fragment (gks 0..48, nf 0..3, term 0..1) = 512 f16 (1KB); lane (kg*32+r)
// holds 8 f16 for col h=nf*32+r, k=gks*16+kg*8+0..7.
__global__ void split_w1(const float* __restrict__ W1, _Float16* __restrict__ wB){
  int i = blockIdx.x * 256 + threadIdx.x;
  if (i < W1N) {
    int h = i / 784, k = i % 784;
    float v = W1[i] * SW;
    _Float16 hi = (_Float16)v;
    _Float16 lo = (_Float16)(v - (float)hi);
    int ks = k >> 4, kg = (k >> 3) & 1, j = k & 7, nf = h >> 5, r = h & 31;
    int base = ((ks * 4 + nf) * 2) * 512 + (kg * 32 + r) * 8 + j;
    wB[base]       = hi;   // term 0
    wB[base + 512] = lo;   // term 1
  }
}

// cur1[m][h] = sum_k x[m][k]*W1[h][k] + b1[h] (scaled acc; bias in epilogue).
// BARRIER-FREE, fully decoupled waves. Wave w owns rows w*32..+32.
// A: wave-private fragment-major LDS, 5-slab rotation (2KB/16-k step), staged
//    via global_load_lds at distance 3. Only this wave reads it.
// B: DOUBLE-BUFFERED in registers (8 x f16x8), distance 1, compiler-tracked —
//    its auto-vmcnt before use keeps A(p+2) in flight (in-order safe).
// Manual VMW(n) guards only gll16->ds_read; n = exact count of ops younger
// than A(p): steady 20 = B(p-1)8 + A(p+1)2 + B(p)8 + A(p+2)2.
// 49 phases fully unrolled; no s_barrier anywhere.
__launch_bounds__(256, 2)
__global__ void gemm1(const float* __restrict__ x,
                      const _Float16* __restrict__ wB,
                      const float* __restrict__ b1,
                      float* __restrict__ cur1,
                      long row0){
  __shared__ float lds[10240];            // 4 waves x 5 slabs x 512 floats = 40KB
  const int lane = threadIdx.x & 63;
  const int w    = threadIdx.x >> 6;
  const long blk_row0 = row0 + (long)blockIdx.x * 128;
  const int r  = lane & 31;
  const int kg = lane >> 5;

  const float* xA = x + (blk_row0 + w * 32 + r) * 784 + kg * 8;  // wave's A rows
  const f16x8* wv = (const f16x8*)wB + lane;
  float* myl = &lds[w * 2560];            // wave-private 10KB (5 x 2KB)

  #define AST(b5, s) {                                                       \
    gll16(xA + (s) * 16,     myl + (b5) * 512);                              \
    gll16(xA + (s) * 16 + 4, myl + (b5) * 512 + 256); }

  #define LDB(dst, s) { _Pragma("unroll") for (int f = 0; f < 8; ++f)        \
      dst[f] = wv[((s) * 8 + f) * 64]; }

  #define VMW(n) { asm volatile("s_waitcnt vmcnt(" #n ")" ::: "memory");     \
                   __builtin_amdgcn_sched_barrier(0); }

  #define CPH(b5, breg) {                                                    \
    fvec4 a0 = *(const fvec4*)(myl + (b5) * 512 + lane * 4);                 \
    fvec4 a1 = *(const fvec4*)(myl + (b5) * 512 + 256 + lane * 4);           \
    f16x8 ah, al;                                                            \
    _Pragma("unroll") for (int j = 0; j < 8; ++j) {                          \
      float v = ((j < 4) ? a0[j] : a1[j - 4]) * SX;                          \
      _Float16 hh = (_Float16)v;                                             \
      ah[j] = hh; al[j] = (_Float16)(v - (float)hh);                         \
    }                                                                        \
    _Pragma("unroll") for (int nf = 0; nf < 4; ++nf) {                       \
      acc[nf] = __builtin_amdgcn_mfma_f32_32x32x16_f16(ah, breg[nf * 2],     acc[nf], 0, 0, 0); \
      acc[nf] = __builtin_amdgcn_mfma_f32_32x32x16_f16(ah, breg[nf * 2 + 1], acc[nf], 0, 0, 0); \
      acc[nf] = __builtin_amdgcn_mfma_f32_32x32x16_f16(al, breg[nf * 2],     acc[nf], 0, 0, 0); \
    } }

  // 10 steady phases starting at p=b (requires b odd, b%5==3)
  #define P10(b) \
    VMW(20); LDB(bA,(b)+1);  CPH(3,bB); AST(1,(b)+3);  \
    VMW(20); LDB(bB,(b)+2);  CPH(4,bA); AST(2,(b)+4);  \
    VMW(20); LDB(bA,(b)+3);  CPH(0,bB); AST(3,(b)+5);  \
    VMW(20); LDB(bB,(b)+4);  CPH(1,bA); AST(4,(b)+6);  \
    VMW(20); LDB(bA,(b)+5);  CPH(2,bB); AST(0,(b)+7);  \
    VMW(20); LDB(bB,(b)+6);  CPH(3,bA); AST(1,(b)+8);  \
    VMW(20); LDB(bA,(b)+7);  CPH(4,bB); AST(2,(b)+9);  \
    VMW(20); LDB(bB,(b)+8);  CPH(0,bA); AST(3,(b)+10); \
    VMW(20); LDB(bA,(b)+9);  CPH(1,bB); AST(4,(b)+11); \
    VMW(20); LDB(bB,(b)+10); CPH(2,bA); AST(0,(b)+12);

  f32x16 acc[4] = {};
  f16x8 bA[8], bB[8];

  // prologue: A slabs 0..2 staged, B(0) in regs
  AST(0, 0); AST(1, 1); AST(2, 2);
  LDB(bA, 0);

  // phases 0..2 (vmcnt counts: 12, 20, 28 — exact younger-op counts)
  VMW(12); LDB(bB, 1); CPH(0, bA); AST(3, 3);
  VMW(20); LDB(bA, 2); CPH(1, bB); AST(4, 4);
  VMW(28); LDB(bB, 3); CPH(2, bA); AST(0, 5);
  // phases 3..42
  P10(3) P10(13) P10(23) P10(33)
  // phases 43..45
  VMW(20); LDB(bA, 44); CPH(3, bB); AST(1, 46);
  VMW(20); LDB(bB, 45); CPH(4, bA); AST(2, 47);
  VMW(20); LDB(bA, 46); CPH(0, bB); AST(3, 48);
  // drain phases 46..48 (no more A stages)
  VMW(20); LDB(bB, 47); CPH(1, bA);
  VMW(18); LDB(bA, 48); CPH(2, bB);
  VMW(16);              CPH(3, bA);

  // C/D layout (m74/m101-verified): col = lane&31, row = (reg&3)+8*(reg>>2)+4*(lane>>5)
  float b1v[4];
  #pragma unroll
  for (int nf = 0; nf < 4; ++nf) b1v[nf] = b1[nf * 32 + r];
  long m0 = (long)blockIdx.x * 128 + w * 32;
  #pragma unroll
  for (int nf = 0; nf < 4; ++nf)
    #pragma unroll
    for (int reg = 0; reg < 16; ++reg) {
      int rr = (reg & 3) + 8 * (reg >> 2) + 4 * kg;
      cur1[(m0 + rr) * 128 + nf * 32 + r] = acc[nf][reg] * SINV + b1v[nf];
    }
  #undef AST
  #undef LDB
  #undef VMW
  #undef CPH
  #undef P10
}

// LIF recurrence + layer 2 (bias1 already folded into cur1).
__launch_bounds__(256)
__global__ void lif(const float* __restrict__ cur1,
                    const float* __restrict__ W2,
                    const float* __restrict__ b2,
                    float* __restrict__ out,
                    float* __restrict__ state1,
                    float* __restrict__ state2,
                    int t0, int tn){
  const int lane = threadIdx.x & 63;
  const int b = blockIdx.x * 4 + (threadIdx.x >> 6);
  const int o = lane & 15;
  const int c = lane >> 4;

  float wv[32];
  #pragma unroll
  for (int j = 0; j < 32; ++j) wv[j] = 0.f;
  if (o < 10) {
    #pragma unroll
    for (int j = 0; j < 32; ++j) wv[j] = W2[o * 128 + c * 32 + j];
  }
  float b2v = (lane < 10) ? b2[lane] : 0.f;

  float mem1a, mem1b, mem2;
  if (t0 == 0) { mem1a = 0.f; mem1b = 0.f; mem2 = 0.f; }
  else {
    mem1a = state1[b * 128 + lane];
    mem1b = state1[b * 128 + 64 + lane];
    mem2  = (lane < 10) ? state2[b * 10 + lane] : 0.f;
  }

  for (int t = t0; t < tn; ++t) {
    long base = ((long)(t - t0) * 4096 + b) * 128;
    float c1a = cur1[base + lane];
    float c1b = cur1[base + 64 + lane];
    float r1a = (mem1a > THR) ? THR : 0.f;
    float r1b = (mem1b > THR) ? THR : 0.f;
    mem1a = BETA * mem1a + c1a - r1a;
    mem1b = BETA * mem1b + c1b - r1b;

    uint64_t mA = __ballot(mem1a > THR);
    uint64_t mB = __ballot(mem1b > THR);
    uint64_t m64 = (c & 2) ? mB : mA;
    uint32_t bits = (uint32_t)(m64 >> ((c & 1) << 5));

    float s = 0.f;
    #pragma unroll
    for (int j = 0; j < 32; ++j)
      s = fmaf((float)((bits >> j) & 1u), wv[j], s);   // bfe+cvt+fma
    s += __shfl_xor(s, 16);
    s += __shfl_xor(s, 32);

    if (lane < 10) {
      float cur2 = s + b2v;
      float r2 = (mem2 > THR) ? THR : 0.f;
      mem2 = BETA * mem2 + cur2 - r2;
      float s2 = (mem2 > THR) ? 1.f : 0.f;
      long ob = (long)t * 40960 + (long)b * 10 + lane;
      out[ob] = s2;
      out[1228800 + ob] = mem2;
    }
  }

  if (tn < 30) {
    state1[b * 128 + lane] = mem1a;
    state1[b * 128 + 64 + lane] = mem1b;
    if (lane < 10) state2[b * 10 + lane] = mem2;
  }
}

extern "C" void kernel_launch(void* const* d_in, const int* in_sizes, int n_in,
                              void* d_out, int out_size, void* d_ws, size_t ws_size,
                              hipStream_t stream) {
  const float* x  = (const float*)d_in[0];
  const float* W1 = (const float*)d_in[1];
  const float* b1 = (const float*)d_in[2];
  const float* W2 = (const float*)d_in[3];
  const float* b2 = (const float*)d_in[4];
  float* out = (float*)d_out;

  const int T = 30, B = 4096;

  char* ws = (char*)d_ws;
  _Float16* wB = (_Float16*)ws;                  // 49*8*512 fp16 = 392KB
  size_t off = (size_t)49 * 8 * 512 * sizeof(_Float16);
  off = (off + 255) & ~(size_t)255;
  float* state1 = (float*)(ws + off); off += (size_t)B * 128 * 4;
  float* state2 = (float*)(ws + off); off += (size_t)B * 10 * 4;
  off = (off + 255) & ~(size_t)255;
  float* cur1 = (float*)(ws + off);

  size_t per_t = (size_t)B * 128 * 4;
  size_t avail = (ws_size > off) ? (ws_size - off) : 0;
  int CH = (int)(avail / per_t);
  if (CH > T) CH = T;
  if (CH < 1) CH = 1;

  split_w1<<<(W1N + 255) / 256, 256, 0, stream>>>(W1, wB);

  for (int t0 = 0; t0 < T; t0 += CH) {
    int tn = (t0 + CH < T) ? (t0 + CH) : T;
    int mrows = (tn - t0) * B;                   // multiple of 4096 -> multiple of 128
    gemm1<<<mrows / 128, 256, 0, stream>>>(x, wB, b1, cur1, (long)t0 * B);
    lif<<<B / 4, 256, 0, stream>>>(cur1, W2, b2, out, state1, state2, t0, tn);
  }
}

// Round 18
// 192.167 us; speedup vs baseline: 1.1161x; 1.1161x over previous
//
#include <hip/hip_runtime.h>
#include <stdint.h>

#define THR  1.0f
#define BETA 0.95f
#define SX   4096.0f            // x scale (2^12) -> no fp16 denormal flush
#define SW   512.0f             // W scale (2^9)
#define SINV (1.0f / (4096.0f * 512.0f))
#define W1N  (128 * 784)

typedef __attribute__((ext_vector_type(8)))  _Float16 f16x8;
typedef __attribute__((ext_vector_type(16))) float    f32x16;
typedef __attribute__((ext_vector_type(4)))  float    fvec4;

__device__ __forceinline__ void gll16(const float* g, float* l){
  __builtin_amdgcn_global_load_lds((const __attribute__((address_space(1))) void*)g,
                                   (__attribute__((address_space(3))) void*)l, 16, 0, 0);
}

// 2-term RNE fp16 split of scaled W1 in per-16k fragment order:
// fragment (gks 0..48, nf 0..3, term 0..1) = 512 f16 (1KB); lane (kg*32+r)
// holds 8 f16 for col h=nf*32+r, k=gks*16+kg*8+0..7.
__global__ void split_w1(const float* __restrict__ W1, _Float16* __restrict__ wB){
  int i = blockIdx.x * 256 + threadIdx.x;
  if (i < W1N) {
    int h = i / 784, k = i % 784;
    float v = W1[i] * SW;
    _Float16 hi = (_Float16)v;
    _Float16 lo = (_Float16)(v - (float)hi);
    int ks = k >> 4, kg = (k >> 3) & 1, j = k & 7, nf = h >> 5, r = h & 31;
    int base = ((ks * 4 + nf) * 2) * 512 + (kg * 32 + r) * 8 + j;
    wB[base]       = hi;   // term 0
    wB[base + 512] = lo;   // term 1
  }
}

// cur1[m][h] = sum_k x[m][k]*W1[h][k] + b1[h] (scaled acc; bias in epilogue).
// Block: 4 waves, tile 128m x 128n. 24 slabs of 32-k + one 16-k tail.
// A: wave-private fragment-major LDS dbuf (2x16KB) + 8KB tail = 40KB LDS.
// B: REGISTER double-buffer (16 x f16x8 per slab) loaded via coalesced 1KB
//    global reads (L1-hot, shared by the 4 barrier-locked waves).
// Phase s: LDB(B,s+1)[16] -> STAGE_A(s+1)[4] -> vmcnt(20) -> s_barrier -> CPH(s).
// In-order ledger: vmcnt(20) keeps exactly {B(s+1)16, A(s+1)4}, retires
// {B(s), A(s)} -> the compiler's hidden wait on B(s) regs is subsumed and
// A prefetch distance stays 1. LDS traffic cut 3.5x vs B-through-LDS.
__launch_bounds__(256, 2)
__global__ void gemm1(const float* __restrict__ x,
                      const _Float16* __restrict__ wB,
                      const float* __restrict__ b1,
                      float* __restrict__ cur1,
                      long row0){
  __shared__ float lds[10240];            // A bufs 2x4096 + tail 2048 floats
  const int lane = threadIdx.x & 63;
  const int w    = threadIdx.x >> 6;
  const long blk_row0 = row0 + (long)blockIdx.x * 128;
  const int r  = lane & 31;
  const int kg = lane >> 5;

  const float* xA = x + (blk_row0 + w * 32 + r) * 784 + kg * 8;  // wave's A rows
  const f16x8* wv = (const f16x8*)wB + lane;

  // stage A of 32-k slab s into LDS buf p (4 gll16/wave, wave-private region)
  #define STAGE_A(p, s) { _Pragma("unroll") for (int ksl = 0; ksl < 2; ++ksl) { \
      gll16(xA + (s) * 32 + ksl * 16,                                        \
            &lds[(p) * 4096 + w * 1024 + ksl * 512]);                        \
      gll16(xA + (s) * 32 + ksl * 16 + 4,                                    \
            &lds[(p) * 4096 + w * 1024 + ksl * 512 + 256]); } }

  // load B of 32-k slab s into a 16 x f16x8 register set (16 coalesced 1KB)
  #define LDB(dst, s) { _Pragma("unroll") for (int f = 0; f < 16; ++f)       \
      dst[f] = wv[((s) * 16 + f) * 64]; }

  // fence: counted vmcnt + barrier + compiler pins
  #define VMB(vm) {                                                         \
    asm volatile("s_waitcnt vmcnt(" #vm ")" ::: "memory");                  \
    __builtin_amdgcn_s_barrier();                                           \
    asm volatile("" ::: "memory");                                          \
    __builtin_amdgcn_sched_barrier(0); }

  // one 16-k step: A from LDS buf p (half ksl), B from regs breg[ksl*8..]
  #define KSTEP(p, breg, ksl) {                                             \
    fvec4 a0 = *(const fvec4*)&lds[(p) * 4096 + w * 1024 + (ksl) * 512 + lane * 4]; \
    fvec4 a1 = *(const fvec4*)&lds[(p) * 4096 + w * 1024 + (ksl) * 512 + 256 + lane * 4]; \
    f16x8 ah, al;                                                           \
    _Pragma("unroll") for (int j = 0; j < 8; ++j) {                         \
      float v = ((j < 4) ? a0[j] : a1[j - 4]) * SX;                         \
      _Float16 hh = (_Float16)v;                                            \
      ah[j] = hh; al[j] = (_Float16)(v - (float)hh);                        \
    }                                                                       \
    _Pragma("unroll") for (int nf = 0; nf < 4; ++nf) {                      \
      acc[nf] = __builtin_amdgcn_mfma_f32_32x32x16_f16(ah, breg[(ksl) * 8 + nf * 2],     acc[nf], 0, 0, 0); \
      acc[nf] = __builtin_amdgcn_mfma_f32_32x32x16_f16(ah, breg[(ksl) * 8 + nf * 2 + 1], acc[nf], 0, 0, 0); \
      acc[nf] = __builtin_amdgcn_mfma_f32_32x32x16_f16(al, breg[(ksl) * 8 + nf * 2],     acc[nf], 0, 0, 0); \
    } }

  #define CPH(p, breg) { KSTEP(p, breg, 0); KSTEP(p, breg, 1); }

  f32x16 acc[4] = {};
  f16x8 bA[16], bB[16];

  // prologue: B(0)->bA, A(0)->buf0, A tail (k=768..783) -> lds[8192..]
  LDB(bA, 0);
  STAGE_A(0, 0);
  gll16(xA + 768,     &lds[8192 + w * 512]);
  gll16(xA + 768 + 4, &lds[8192 + w * 512 + 256]);

  // phases 0..21 (11 unrolled pairs)
  for (int q = 0; q < 11; ++q) {
    const int s = 2 * q;
    LDB(bB, s + 1); STAGE_A(1, s + 1); VMB(20); CPH(0, bA);   // phase s (even)
    LDB(bA, s + 2); STAGE_A(0, s + 2); VMB(20); CPH(1, bB);   // phase s+1 (odd)
  }
  // phase 22: stage/load slab 23
  LDB(bB, 23); STAGE_A(1, 23); VMB(20); CPH(0, bA);
  // phase 23: load tail B (gks=48, 8 frags) into bA[0..7]
  #pragma unroll
  for (int f = 0; f < 8; ++f) bA[f] = wv[(48 * 8 + f) * 64];
  VMB(8); CPH(1, bB);
  // tail 16-k step (gks=48): A from tail LDS, B from bA[0..7]
  {
    asm volatile("s_waitcnt vmcnt(0)" ::: "memory");
    __builtin_amdgcn_sched_barrier(0);
    fvec4 a0 = *(const fvec4*)&lds[8192 + w * 512 + lane * 4];
    fvec4 a1 = *(const fvec4*)&lds[8192 + w * 512 + 256 + lane * 4];
    f16x8 ah, al;
    #pragma unroll
    for (int j = 0; j < 8; ++j) {
      float v = ((j < 4) ? a0[j] : a1[j - 4]) * SX;
      _Float16 hh = (_Float16)v;
      ah[j] = hh; al[j] = (_Float16)(v - (float)hh);
    }
    #pragma unroll
    for (int nf = 0; nf < 4; ++nf) {
      acc[nf] = __builtin_amdgcn_mfma_f32_32x32x16_f16(ah, bA[nf * 2],     acc[nf], 0, 0, 0);
      acc[nf] = __builtin_amdgcn_mfma_f32_32x32x16_f16(ah, bA[nf * 2 + 1], acc[nf], 0, 0, 0);
      acc[nf] = __builtin_amdgcn_mfma_f32_32x32x16_f16(al, bA[nf * 2],     acc[nf], 0, 0, 0);
    }
  }

  // C/D layout (m74/m101-verified): col = lane&31, row = (reg&3)+8*(reg>>2)+4*(lane>>5)
  float b1v[4];
  #pragma unroll
  for (int nf = 0; nf < 4; ++nf) b1v[nf] = b1[nf * 32 + r];
  long m0 = (long)blockIdx.x * 128 + w * 32;
  #pragma unroll
  for (int nf = 0; nf < 4; ++nf)
    #pragma unroll
    for (int reg = 0; reg < 16; ++reg) {
      int rr = (reg & 3) + 8 * (reg >> 2) + 4 * kg;
      cur1[(m0 + rr) * 128 + nf * 32 + r] = acc[nf][reg] * SINV + b1v[nf];
    }
  #undef STAGE_A
  #undef LDB
  #undef VMB
  #undef KSTEP
  #undef CPH
}

// LIF recurrence + layer 2 (bias1 already folded into cur1).
__launch_bounds__(256)
__global__ void lif(const float* __restrict__ cur1,
                    const float* __restrict__ W2,
                    const float* __restrict__ b2,
                    float* __restrict__ out,
                    float* __restrict__ state1,
                    float* __restrict__ state2,
                    int t0, int tn){
  const int lane = threadIdx.x & 63;
  const int b = blockIdx.x * 4 + (threadIdx.x >> 6);
  const int o = lane & 15;
  const int c = lane >> 4;

  float wv[32];
  #pragma unroll
  for (int j = 0; j < 32; ++j) wv[j] = 0.f;
  if (o < 10) {
    #pragma unroll
    for (int j = 0; j < 32; ++j) wv[j] = W2[o * 128 + c * 32 + j];
  }
  float b2v = (lane < 10) ? b2[lane] : 0.f;

  float mem1a, mem1b, mem2;
  if (t0 == 0) { mem1a = 0.f; mem1b = 0.f; mem2 = 0.f; }
  else {
    mem1a = state1[b * 128 + lane];
    mem1b = state1[b * 128 + 64 + lane];
    mem2  = (lane < 10) ? state2[b * 10 + lane] : 0.f;
  }

  for (int t = t0; t < tn; ++t) {
    long base = ((long)(t - t0) * 4096 + b) * 128;
    float c1a = cur1[base + lane];
    float c1b = cur1[base + 64 + lane];
    float r1a = (mem1a > THR) ? THR : 0.f;
    float r1b = (mem1b > THR) ? THR : 0.f;
    mem1a = BETA * mem1a + c1a - r1a;
    mem1b = BETA * mem1b + c1b - r1b;

    uint64_t mA = __ballot(mem1a > THR);
    uint64_t mB = __ballot(mem1b > THR);
    uint64_t m64 = (c & 2) ? mB : mA;
    uint32_t bits = (uint32_t)(m64 >> ((c & 1) << 5));

    float s = 0.f;
    #pragma unroll
    for (int j = 0; j < 32; ++j)
      s = fmaf((float)((bits >> j) & 1u), wv[j], s);   // bfe+cvt+fma
    s += __shfl_xor(s, 16);
    s += __shfl_xor(s, 32);

    if (lane < 10) {
      float cur2 = s + b2v;
      float r2 = (mem2 > THR) ? THR : 0.f;
      mem2 = BETA * mem2 + cur2 - r2;
      float s2 = (mem2 > THR) ? 1.f : 0.f;
      long ob = (long)t * 40960 + (long)b * 10 + lane;
      out[ob] = s2;
      out[1228800 + ob] = mem2;
    }
  }

  if (tn < 30) {
    state1[b * 128 + lane] = mem1a;
    state1[b * 128 + 64 + lane] = mem1b;
    if (lane < 10) state2[b * 10 + lane] = mem2;
  }
}

extern "C" void kernel_launch(void* const* d_in, const int* in_sizes, int n_in,
                              void* d_out, int out_size, void* d_ws, size_t ws_size,
                              hipStream_t stream) {
  const float* x  = (const float*)d_in[0];
  const float* W1 = (const float*)d_in[1];
  const float* b1 = (const float*)d_in[2];
  const float* W2 = (const float*)d_in[3];
  const float* b2 = (const float*)d_in[4];
  float* out = (float*)d_out;

  const int T = 30, B = 4096;

  char* ws = (char*)d_ws;
  _Float16* wB = (_Float16*)ws;                  // 49*8*512 fp16 = 392KB
  size_t off = (size_t)49 * 8 * 512 * sizeof(_Float16);
  off = (off + 255) & ~(size_t)255;
  float* state1 = (float*)(ws + off); off += (size_t)B * 128 * 4;
  float* state2 = (float*)(ws + off); off += (size_t)B * 10 * 4;
  off = (off + 255) & ~(size_t)255;
  float* cur1 = (float*)(ws + off);

  size_t per_t = (size_t)B * 128 * 4;
  size_t avail = (ws_size > off) ? (ws_size - off) : 0;
  int CH = (int)(avail / per_t);
  if (CH > T) CH = T;
  if (CH < 1) CH = 1;

  split_w1<<<(W1N + 255) / 256, 256, 0, stream>>>(W1, wB);

  for (int t0 = 0; t0 < T; t0 += CH) {
    int tn = (t0 + CH < T) ? (t0 + CH) : T;
    int mrows = (tn - t0) * B;                   // multiple of 4096 -> multiple of 128
    gemm1<<<mrows / 128, 256, 0, stream>>>(x, wB, b1, cur1, (long)t0 * B);
    lif<<<B / 4, 256, 0, stream>>>(cur1, W2, b2, out, state1, state2, t0, tn);
  }
}

// Round 19
// 153.962 us; speedup vs baseline: 1.3931x; 1.2481x over previous
//
#include <hip/hip_runtime.h>
#include <stdint.h>

#define THR  1.0f
#define BETA 0.95f
#define SX   4096.0f            // x scale (2^12) -> no fp16 denormal flush
#define SW   512.0f             // W scale (2^9)
#define SINV (1.0f / (4096.0f * 512.0f))
#define W1N  (128 * 784)

typedef __attribute__((ext_vector_type(8)))  _Float16 f16x8;
typedef __attribute__((ext_vector_type(16))) float    f32x16;
typedef __attribute__((ext_vector_type(4)))  float    fvec4;

__device__ __forceinline__ void gll16(const float* g, float* l){
  __builtin_amdgcn_global_load_lds((const __attribute__((address_space(1))) void*)g,
                                   (__attribute__((address_space(3))) void*)l, 16, 0, 0);
}

// 2-term RNE fp16 split of scaled W1 in per-16k fragment order:
// fragment (gks 0..48, nf 0..3, term 0..1) = 512 f16 (1KB); lane (kg*32+r)
// holds 8 f16 for col h=nf*32+r, k=gks*16+kg*8+0..7.
__global__ void split_w1(const float* __restrict__ W1, _Float16* __restrict__ wB){
  int i = blockIdx.x * 256 + threadIdx.x;
  if (i < W1N) {
    int h = i / 784, k = i % 784;
    float v = W1[i] * SW;
    _Float16 hi = (_Float16)v;
    _Float16 lo = (_Float16)(v - (float)hi);
    int ks = k >> 4, kg = (k >> 3) & 1, j = k & 7, nf = h >> 5, r = h & 31;
    int base = ((ks * 4 + nf) * 2) * 512 + (kg * 32 + r) * 8 + j;
    wB[base]       = hi;   // term 0
    wB[base + 512] = lo;   // term 1
  }
}

// cur1[m][h] = sum_k x[m][k]*W1[h][k] + b1[h] (scaled acc; bias in epilogue).
// Block: 8 waves (512 thr), tile 256m x 128n; wave grid 4(M) x 2(N):
// wave (wm,wn) owns rows wm*64..+64, cols wn*64..+64 (acc 4 x f32x16).
// R7's proven fence pattern (FENCE_A lgkm-drain + FENCE_B counted vmcnt),
// fully COALESCED staging (A: 8 lanes/row XOR-swizzled; B: linear), B-LDS.
// 24 slabs of 32-k + 16-k tail. LDS 120KB -> 1 block/CU, 8-wave interleave.
// Each wave reads only its 2 N-fragments -> B LDS reads halved vs 128-tile.
__launch_bounds__(512, 2)
__global__ void gemm1(const float* __restrict__ x,
                      const float* __restrict__ wBf,   // wB viewed as float*
                      const float* __restrict__ b1,
                      float* __restrict__ cur1,
                      long row0){
  __shared__ float lds[30720];  // A 2x8192 | B@16384 2x4096 | Atail@24576 4096 | Btail@28672 2048
  const int lane = threadIdx.x & 63;
  const int w    = threadIdx.x >> 6;    // 0..7
  const int wm   = w >> 1;              // 0..3  (M group)
  const int wn   = w & 1;               // 0..1  (N group)
  const long blk_row0 = row0 + (long)blockIdx.x * 256;
  const int r  = lane & 31;
  const int kg = lane >> 5;
  const int row_a = wm * 64;            // wave's first A row (frag row = row_a+mf*32+r)

  // stage A of 32-k slab s into buf p: 4 gll16/wave, 8 lanes/row coalesced,
  // XOR-swizzled source so linear LDS dest yields swizzled storage (R7 scheme)
  #define STAGE_A(p, s) { _Pragma("unroll") for (int i = 0; i < 4; ++i) {    \
      int j = w * 4 + i;                 /* 0..31 */                         \
      int jj = j * 64 + lane;            /* 0..2047 */                       \
      int rw = jj >> 3, q = (jj & 7) << 4;                                   \
      int kb = q ^ ((rw & 7) << 4);                                          \
      gll16(x + (blk_row0 + rw) * 784 + (s) * 32 + (kb >> 2),                \
            &lds[(p) * 8192 + j * 256]); } }

  // stage B of 32-k slab s into buf p: 2 gll16/wave, linear (frag-ordered src)
  #define STAGE_B(p, s) { _Pragma("unroll") for (int i = 0; i < 2; ++i) {    \
      int j = w * 2 + i;                 /* 0..15 */                         \
      gll16(wBf + (s) * 4096 + j * 256 + lane * 4,                           \
            &lds[16384 + (p) * 4096 + j * 256]); } }

  #define STAGE(p, s) { STAGE_A(p, s); STAGE_B(p, s); }

  // one 16-k step from buf p: per wave 4 B-frags (its 2 nfl x 2 terms),
  // 2 mf A-fragments (XOR-swizzled ds_read_b128), 12 MFMA
  #define KSTEP(p, ksl) {                                                    \
    f16x8 b[4];                                                              \
    _Pragma("unroll") for (int nfl = 0; nfl < 2; ++nfl)                      \
      _Pragma("unroll") for (int t = 0; t < 2; ++t)                          \
        b[nfl * 2 + t] = *(const f16x8*)&lds[16384 + (p) * 4096 +            \
            ((ksl) * 8 + (wn * 2 + nfl) * 2 + t) * 256 + lane * 4];          \
    _Pragma("unroll") for (int mf = 0; mf < 2; ++mf) {                       \
      int ra = row_a + mf * 32 + r;                                          \
      int xr = (ra & 7) << 4;                                                \
      int kb0 = (ksl) * 64 + kg * 32;                                        \
      fvec4 a0 = *(const fvec4*)&lds[(p) * 8192 + ra * 32 + (((kb0)      ^ xr) >> 2)]; \
      fvec4 a1 = *(const fvec4*)&lds[(p) * 8192 + ra * 32 + (((kb0 + 16) ^ xr) >> 2)]; \
      f16x8 ah, al;                                                          \
      _Pragma("unroll") for (int j = 0; j < 8; ++j) {                        \
        float v = ((j < 4) ? a0[j] : a1[j - 4]) * SX;                        \
        _Float16 hh = (_Float16)v;                                           \
        ah[j] = hh; al[j] = (_Float16)(v - (float)hh);                       \
      }                                                                      \
      _Pragma("unroll") for (int nfl = 0; nfl < 2; ++nfl) {                  \
        acc[mf * 2 + nfl] = __builtin_amdgcn_mfma_f32_32x32x16_f16(ah, b[nfl * 2],     acc[mf * 2 + nfl], 0, 0, 0); \
        acc[mf * 2 + nfl] = __builtin_amdgcn_mfma_f32_32x32x16_f16(ah, b[nfl * 2 + 1], acc[mf * 2 + nfl], 0, 0, 0); \
        acc[mf * 2 + nfl] = __builtin_amdgcn_mfma_f32_32x32x16_f16(al, b[nfl * 2],     acc[mf * 2 + nfl], 0, 0, 0); \
      } } }

  #define CPH(p) { KSTEP(p, 0); KSTEP(p, 1); }

  #define FENCE_A() { __builtin_amdgcn_sched_barrier(0);                     \
    asm volatile("s_waitcnt lgkmcnt(0)" ::: "memory");                       \
    __builtin_amdgcn_s_barrier();                                            \
    asm volatile("" ::: "memory"); }
  #define FENCE_B(vm) {                                                      \
    asm volatile("s_waitcnt vmcnt(" #vm ")" ::: "memory");                   \
    __builtin_amdgcn_s_barrier();                                            \
    asm volatile("" ::: "memory");                                           \
    __builtin_amdgcn_sched_barrier(0); }

  f32x16 acc[4] = {};

  // ---- prologue: tails + slab0 + slab1 ----
  // A tail (k=768..783, 256 rows x 16 f): 2 gll16/wave, 4 lanes/row, mod-4 swizzle
  #pragma unroll
  for (int i = 0; i < 2; ++i) {
    int j = w * 2 + i;                  // 0..15
    int jj = j * 64 + lane;             // 0..1023
    int rw = jj >> 2, q = (jj & 3) << 4;
    int kb = q ^ ((rw & 3) << 4);
    gll16(x + (blk_row0 + rw) * 784 + 768 + (kb >> 2), &lds[24576 + j * 256]);
  }
  // B tail (gks=48): 1 gll16/wave
  gll16(wBf + 24 * 4096 + w * 256 + lane * 4, &lds[28672 + w * 256]);
  STAGE(0, 0);
  STAGE(1, 1);
  FENCE_B(6);                           // tails+slab0 landed; slab1 (6 ops) in flight
  CPH(0);

  // ---- main loop: slabs 1..22 ----
  for (int q = 0; q < 11; ++q) {
    const int s = 2 * q + 1;
    FENCE_A(); STAGE(0, s + 1); FENCE_B(6); CPH(1);
    FENCE_A(); STAGE(1, s + 2); FENCE_B(6); CPH(0);
  }
  // ---- final slab 23 + 16-k tail ----
  FENCE_A();
  FENCE_B(0);
  CPH(1);
  {
    f16x8 b[4];
    #pragma unroll
    for (int nfl = 0; nfl < 2; ++nfl)
      #pragma unroll
      for (int t = 0; t < 2; ++t)
        b[nfl * 2 + t] = *(const f16x8*)&lds[28672 + ((wn * 2 + nfl) * 2 + t) * 256 + lane * 4];
    #pragma unroll
    for (int mf = 0; mf < 2; ++mf) {
      int ra = row_a + mf * 32 + r;
      int xr3 = (ra & 3) << 4;
      int kb0 = kg * 32;
      fvec4 a0 = *(const fvec4*)&lds[24576 + ra * 16 + (((kb0)      ^ xr3) >> 2)];
      fvec4 a1 = *(const fvec4*)&lds[24576 + ra * 16 + (((kb0 + 16) ^ xr3) >> 2)];
      f16x8 ah, al;
      #pragma unroll
      for (int j = 0; j < 8; ++j) {
        float v = ((j < 4) ? a0[j] : a1[j - 4]) * SX;
        _Float16 hh = (_Float16)v;
        ah[j] = hh; al[j] = (_Float16)(v - (float)hh);
      }
      #pragma unroll
      for (int nfl = 0; nfl < 2; ++nfl) {
        acc[mf * 2 + nfl] = __builtin_amdgcn_mfma_f32_32x32x16_f16(ah, b[nfl * 2],     acc[mf * 2 + nfl], 0, 0, 0);
        acc[mf * 2 + nfl] = __builtin_amdgcn_mfma_f32_32x32x16_f16(ah, b[nfl * 2 + 1], acc[mf * 2 + nfl], 0, 0, 0);
        acc[mf * 2 + nfl] = __builtin_amdgcn_mfma_f32_32x32x16_f16(al, b[nfl * 2],     acc[mf * 2 + nfl], 0, 0, 0);
      }
    }
  }

  // C/D layout (m74/m101-verified): col = lane&31, row = (reg&3)+8*(reg>>2)+4*(lane>>5)
  float b1v[2];
  #pragma unroll
  for (int nfl = 0; nfl < 2; ++nfl) b1v[nfl] = b1[wn * 64 + nfl * 32 + r];
  long m0 = (long)blockIdx.x * 256 + wm * 64;
  #pragma unroll
  for (int mf = 0; mf < 2; ++mf)
    #pragma unroll
    for (int nfl = 0; nfl < 2; ++nfl)
      #pragma unroll
      for (int reg = 0; reg < 16; ++reg) {
        int rr = (reg & 3) + 8 * (reg >> 2) + 4 * kg;
        cur1[(m0 + mf * 32 + rr) * 128 + wn * 64 + nfl * 32 + r] =
            acc[mf * 2 + nfl][reg] * SINV + b1v[nfl];
      }
  #undef STAGE_A
  #undef STAGE_B
  #undef STAGE
  #undef KSTEP
  #undef CPH
  #undef FENCE_A
  #undef FENCE_B
}

// LIF recurrence + layer 2 (bias1 already folded into cur1).
__launch_bounds__(256)
__global__ void lif(const float* __restrict__ cur1,
                    const float* __restrict__ W2,
                    const float* __restrict__ b2,
                    float* __restrict__ out,
                    float* __restrict__ state1,
                    float* __restrict__ state2,
                    int t0, int tn){
  const int lane = threadIdx.x & 63;
  const int b = blockIdx.x * 4 + (threadIdx.x >> 6);
  const int o = lane & 15;
  const int c = lane >> 4;

  float wv[32];
  #pragma unroll
  for (int j = 0; j < 32; ++j) wv[j] = 0.f;
  if (o < 10) {
    #pragma unroll
    for (int j = 0; j < 32; ++j) wv[j] = W2[o * 128 + c * 32 + j];
  }
  float b2v = (lane < 10) ? b2[lane] : 0.f;

  float mem1a, mem1b, mem2;
  if (t0 == 0) { mem1a = 0.f; mem1b = 0.f; mem2 = 0.f; }
  else {
    mem1a = state1[b * 128 + lane];
    mem1b = state1[b * 128 + 64 + lane];
    mem2  = (lane < 10) ? state2[b * 10 + lane] : 0.f;
  }

  for (int t = t0; t < tn; ++t) {
    long base = ((long)(t - t0) * 4096 + b) * 128;
    float c1a = cur1[base + lane];
    float c1b = cur1[base + 64 + lane];
    float r1a = (mem1a > THR) ? THR : 0.f;
    float r1b = (mem1b > THR) ? THR : 0.f;
    mem1a = BETA * mem1a + c1a - r1a;
    mem1b = BETA * mem1b + c1b - r1b;

    uint64_t mA = __ballot(mem1a > THR);
    uint64_t mB = __ballot(mem1b > THR);
    uint64_t m64 = (c & 2) ? mB : mA;
    uint32_t bits = (uint32_t)(m64 >> ((c & 1) << 5));

    float s = 0.f;
    #pragma unroll
    for (int j = 0; j < 32; ++j)
      s = fmaf((float)((bits >> j) & 1u), wv[j], s);   // bfe+cvt+fma
    s += __shfl_xor(s, 16);
    s += __shfl_xor(s, 32);

    if (lane < 10) {
      float cur2 = s + b2v;
      float r2 = (mem2 > THR) ? THR : 0.f;
      mem2 = BETA * mem2 + cur2 - r2;
      float s2 = (mem2 > THR) ? 1.f : 0.f;
      long ob = (long)t * 40960 + (long)b * 10 + lane;
      out[ob] = s2;
      out[1228800 + ob] = mem2;
    }
  }

  if (tn < 30) {
    state1[b * 128 + lane] = mem1a;
    state1[b * 128 + 64 + lane] = mem1b;
    if (lane < 10) state2[b * 10 + lane] = mem2;
  }
}

extern "C" void kernel_launch(void* const* d_in, const int* in_sizes, int n_in,
                              void* d_out, int out_size, void* d_ws, size_t ws_size,
                              hipStream_t stream) {
  const float* x  = (const float*)d_in[0];
  const float* W1 = (const float*)d_in[1];
  const float* b1 = (const float*)d_in[2];
  const float* W2 = (const float*)d_in[3];
  const float* b2 = (const float*)d_in[4];
  float* out = (float*)d_out;

  const int T = 30, B = 4096;

  char* ws = (char*)d_ws;
  _Float16* wB = (_Float16*)ws;                  // 49*8*512 fp16 = 392KB
  size_t off = (size_t)49 * 8 * 512 * sizeof(_Float16);
  off = (off + 255) & ~(size_t)255;
  float* state1 = (float*)(ws + off); off += (size_t)B * 128 * 4;
  float* state2 = (float*)(ws + off); off += (size_t)B * 10 * 4;
  off = (off + 255) & ~(size_t)255;
  float* cur1 = (float*)(ws + off);

  size_t per_t = (size_t)B * 128 * 4;
  size_t avail = (ws_size > off) ? (ws_size - off) : 0;
  int CH = (int)(avail / per_t);
  if (CH > T) CH = T;
  if (CH < 1) CH = 1;

  split_w1<<<(W1N + 255) / 256, 256, 0, stream>>>(W1, wB);

  for (int t0 = 0; t0 < T; t0 += CH) {
    int tn = (t0 + CH < T) ? (t0 + CH) : T;
    int mrows = (tn - t0) * B;                   // multiple of 4096 -> multiple of 256
    gemm1<<<mrows / 256, 512, 0, stream>>>(x, (const float*)wB, b1, cur1, (long)t0 * B);
    lif<<<B / 4, 256, 0, stream>>>(cur1, W2, b2, out, state1, state2, t0, tn);
  }
}